// Round 1
// baseline (98.847 us; speedup 1.0000x reference)
//
#include <hip/hip_runtime.h>
#include <hip/hip_fp16.h>

// MinibatchDiscrimination  B=256, IN_F=1024, OUT_F=128, KD=16 (fp32 in/out)
// out[b] = concat(x[b], o_b[b]); o_b[b][o] = sum_b2 exp(-L1(m[b,o,:], m[b2,o,:])) - 1
//
// R10: FULL FUSION — kill the workspace.
//  Evidence (R9 rocprof): top-5 dispatches are harness poison fills of d_ws
//  (268 MB @ ~41 us, 82% HBM peak) inside the timed graph; k_gemm+k_pair were
//  only ~31 us of the 88. The o-slices are independent: block (o,h) recomputes
//  m[:,o,:] itself (A = x, B = T[:,o,:], 512 MFMAs) into LDS and runs the pair
//  phase in-place. Removes: mh HBM round-trip, one launch, inter-kernel stall,
//  and (hypothesis) the 268 MB ws poison from the timed path.
//  Cost: x re-read per block = 1 MB from L2 (268 MB aggregate ~ 8 us, vs
//  128 MB in the split k_gemm) — cheap vs what it buys.
// Numerics identical to R1-R9 (absmax=0.0): bf16-trunc inputs; cross-pair
// norms ~580 -> expf underflows to exact 0; self-pair diff bitwise 0 (same
// LDS row) -> +1 exactly, -1 in epilogue.

#define BATCH 256
#define INF   1024
#define OUTF  128
#define KDIM  16
#define TCOLS 2048
#define OCOLS 1152
#define XB    1032   // bs row = 2064 B = 129*16: 16B-aligned, bank shift 4/row,
                     // b128 frag reads <=2-way aliased = free (m136)

typedef __attribute__((ext_vector_type(8))) short short8;
typedef __attribute__((ext_vector_type(4))) float f32x4;

// pack two fp32 -> two bf16 (trunc) in one v_perm: low16 = lo, high16 = hi
__device__ inline unsigned pack_bf2(float lo, float hi) {
    return __builtin_amdgcn_perm(__float_as_uint(hi), __float_as_uint(lo), 0x07060302u);
}
__device__ inline unsigned short bf_trunc(float f) {
    return (unsigned short)(__float_as_uint(f) >> 16);
}

// ---------------------------------------------------------------- k_fused
// Grid 256 = (o 0..127, h 0..1), 1024 thr = 16 waves, 1 block/CU.
// Phase 1 (GEMM): stage B-slice bf16 to LDS (4 passes); wave w computes
//   m-rows w*16..w*16+15 via 16x16x32 MFMA, A-frags from global x with
//   4-stage register prefetch (8 float4 in flight), in-reg fp32->bf16 pack.
// Phase 2 (pair): identical to R9 k_pair, reading pm from LDS directly.
__global__ __launch_bounds__(1024, 1) void k_fused(const float* __restrict__ x,
                                                   const float* __restrict__ T,
                                                   float* __restrict__ out) {
    const int blk = blockIdx.x;
    const int o   = blk & 127;
    const int h   = blk >> 7;
    const int tid = threadIdx.x;
    const int wave = tid >> 6, lane = tid & 63;
    const int l15 = lane & 15, q = lane >> 4;

    __shared__ unsigned short bs[16][XB];   // 33,024 B  (dead after GEMM)
    __shared__ __half2 pm[BATCH][8];        //  8,192 B  [b][kd/2]
    __shared__ float part[32][128];         // 16,384 B  [bsel][b1-local]

    // prologue: copy x row blk into out (cols 0..1023); blocks <-> rows 1:1
    if (tid < 256)
        reinterpret_cast<float4*>(out)[blk * 288 + tid] =
            reinterpret_cast<const float4*>(x)[blk * 256 + tid];

    // stage B: bs[n][k] = bf16(T[k][o*16+n]); 4 passes x 256 k-rows
    {
        const int kb = tid >> 2, n0 = (tid & 3) * 4;
        #pragma unroll
        for (int pass = 0; pass < 4; ++pass) {
            const int k = pass * 256 + kb;
            float4 v = *reinterpret_cast<const float4*>(&T[k * TCOLS + o * KDIM + n0]);
            bs[n0 + 0][k] = bf_trunc(v.x);
            bs[n0 + 1][k] = bf_trunc(v.y);
            bs[n0 + 2][k] = bf_trunc(v.z);
            bs[n0 + 3][k] = bf_trunc(v.w);
        }
    }
    __syncthreads();

    // K-loop with 4-stage register prefetch. A-frag: A[m=l15][k=q*8+j] (m89/m91).
    const float* xr = &x[(wave * 16 + l15) * INF + q * 8];

    float4 st[4][2];
    #pragma unroll
    for (int p = 0; p < 4; ++p) {
        st[p][0] = *reinterpret_cast<const float4*>(xr + p * 32);
        st[p][1] = *reinterpret_cast<const float4*>(xr + p * 32 + 4);
    }
    f32x4 acc = {0.f, 0.f, 0.f, 0.f};
    #pragma unroll
    for (int ks = 0; ks < 32; ++ks) {
        const int p = ks & 3;
        float4 a0 = st[p][0], a1 = st[p][1];
        const int kn = (ks + 4 < 32) ? ks + 4 : ks;   // tail: dead reload, harmless
        st[p][0] = *reinterpret_cast<const float4*>(xr + kn * 32);
        st[p][1] = *reinterpret_cast<const float4*>(xr + kn * 32 + 4);
        short8 bfr = *reinterpret_cast<const short8*>(&bs[l15][ks * 32 + q * 8]);
        union { unsigned u[4]; short8 s; } ua;
        ua.u[0] = pack_bf2(a0.x, a0.y); ua.u[1] = pack_bf2(a0.z, a0.w);
        ua.u[2] = pack_bf2(a1.x, a1.y); ua.u[3] = pack_bf2(a1.z, a1.w);
        acc = __builtin_amdgcn_mfma_f32_16x16x32_bf16(ua.s, bfr, acc, 0, 0, 0);
    }

    // D layout (m89/m91): col(=kd)=l15, row(=b within 16-tile)=q*4+r
    {
        __half* pmh = reinterpret_cast<__half*>(pm);
        #pragma unroll
        for (int r = 0; r < 4; ++r)
            pmh[(wave * 16 + q * 4 + r) * 16 + l15] = __float2half(acc[r]);
    }
    __syncthreads();

    // pair phase: i1 = tid&31, bsel = tid>>5; 4 b1-rows {h*128 + r*32 + i1}
    // vs b2 in [bsel*8, bsel*8+8). co read wave-uniform -> LDS broadcast.
    const int i1 = tid & 31;
    const int bsel = tid >> 5;            // 0..31
    __half2 my[4][8];
    #pragma unroll
    for (int r = 0; r < 4; ++r) {
        union { uint4 u[2]; __half2 hh[8]; } c;
        c.u[0] = *reinterpret_cast<const uint4*>(&pm[h * 128 + r * 32 + i1][0]);
        c.u[1] = *reinterpret_cast<const uint4*>(&pm[h * 128 + r * 32 + i1][4]);
        #pragma unroll
        for (int j = 0; j < 8; ++j) my[r][j] = c.hh[j];
    }

    float tot[4] = {0.f, 0.f, 0.f, 0.f};
    const int b2_lo = bsel * 8;
    #pragma unroll
    for (int b2 = b2_lo; b2 < b2_lo + 8; ++b2) {
        union { uint4 u[2]; __half2 hh[8]; } co;      // wave-uniform -> broadcast
        co.u[0] = *reinterpret_cast<const uint4*>(&pm[b2][0]);
        co.u[1] = *reinterpret_cast<const uint4*>(&pm[b2][4]);
        #pragma unroll
        for (int r = 0; r < 4; ++r) {
            __half2 e0 = __habs2(__hsub2(my[r][0], co.hh[0]));
            __half2 e1 = __habs2(__hsub2(my[r][1], co.hh[1]));
            __half2 e2 = __habs2(__hsub2(my[r][2], co.hh[2]));
            __half2 e3 = __habs2(__hsub2(my[r][3], co.hh[3]));
            e0 = __hadd2(e0, __habs2(__hsub2(my[r][4], co.hh[4])));
            e1 = __hadd2(e1, __habs2(__hsub2(my[r][5], co.hh[5])));
            e2 = __hadd2(e2, __habs2(__hsub2(my[r][6], co.hh[6])));
            e3 = __hadd2(e3, __habs2(__hsub2(my[r][7], co.hh[7])));
            __half2 es = __hadd2(__hadd2(e0, e1), __hadd2(e2, e3));
            float n = __low2float(es) + __high2float(es);
            tot[r] += __expf(-n);   // b2==b1: same pm row -> diff bitwise 0 -> +1 exact
        }
    }
    #pragma unroll
    for (int r = 0; r < 4; ++r)
        part[bsel][r * 32 + i1] = tot[r];
    __syncthreads();

    // epilogue: sum 32 bsel partials; -1 removes self-pair. One writer per (b,o).
    if (tid < 128) {
        float s = -1.0f;
        #pragma unroll
        for (int j = 0; j < 32; ++j) s += part[j][tid];
        out[(h * 128 + tid) * OCOLS + INF + o] = s;
    }
}

// ---------------------------------------------------------------- launch
extern "C" void kernel_launch(void* const* d_in, const int* in_sizes, int n_in,
                              void* d_out, int out_size, void* d_ws, size_t ws_size,
                              hipStream_t stream) {
    const float* x = (const float*)d_in[0];   // [256][1024]
    const float* T = (const float*)d_in[1];   // [1024][2048]
    float* out = (float*)d_out;               // [256][1152]
    (void)d_ws; (void)ws_size;                // workspace intentionally unused (R10)

    k_fused<<<256, 1024, 0, stream>>>(x, T, out);
}

// Round 2
// 86.742 us; speedup vs baseline: 1.1395x; 1.1395x over previous
//
#include <hip/hip_runtime.h>
#include <hip/hip_fp16.h>

// MinibatchDiscrimination  B=256, IN_F=1024, OUT_F=128, KD=16 (fp32 in/out)
// out[b] = concat(x[b], o_b[b]); o_b[b][o] = sum_b2 exp(-L1(m[b,o,:], m[b2,o,:])) - 1
//
// R11: fused kernel kept; fix the GEMM-phase stall R10 exposed.
//  Evidence (R10 rocprof): k_fused 43.6 us, VGPR_Count=32 -> the st[4][2]
//  float4 prefetch (needs 32 VGPR alone) collapsed to load-use serialization;
//  MfmaUtil 1.7 / VALUBusy 15.7 -> ~85% stalled, dominated by 256 MB of fp32
//  x re-reads through ~1 outstanding load/wave. Fill (268 MB, ~41 us) proven
//  to stay in the timed graph regardless of d_ws use -> fixed cost ~55 us;
//  only kernel time is contestable.
//  Changes:
//   - k_prep: x -> bf16 xs[256][1024] in ws (same bf_trunc values as before
//     -> bitwise-identical MFMA -> absmax 0.0 preserved). Halves x bytes and
//     deletes 4 v_perm packs per K-iter.
//   - GEMM A-path: two 16-deep short8 prefetch bursts pinned with
//     sched_barrier(0); one base reg + imm offsets (<=2KB, 13-bit signed) ->
//     16 loads in flight. __launch_bounds__(1024,4) targets the 128-VGPR cap
//     a 16-wave block allows (a[16]=64 + misc ~= 100).
//   - T staging: 4 float4 batched before LDS stores (4 in flight).
//  Pair phase unchanged (known-good from R9).
// Numerics (R1-R10, absmax=0.0): bf16-trunc inputs; cross-pair norms ~580 ->
// expf underflows to exact 0; self-pair diff bitwise 0 -> +1 exact, -1 at end.

#define BATCH 256
#define INF   1024
#define OUTF  128
#define KDIM  16
#define TCOLS 2048
#define OCOLS 1152
#define XB    1032   // bs row = 2064 B = 129*16: 16B-aligned, bank shift 4/row,
                     // b128 frag reads <=2-way aliased = free (m136)

typedef __attribute__((ext_vector_type(8))) short short8;
typedef __attribute__((ext_vector_type(4))) float f32x4;
typedef __attribute__((ext_vector_type(4))) unsigned short ushort4v;

__device__ inline unsigned short bf_trunc(float f) {
    return (unsigned short)(__float_as_uint(f) >> 16);
}

// ---------------------------------------------------------------- k_prep
// x fp32 [256][1024] -> xs bf16 [256][1024] (row-major, trunc). 64K float4s.
__global__ __launch_bounds__(256) void k_prep(const float* __restrict__ x,
                                              unsigned short* __restrict__ xs) {
    const int i = blockIdx.x * 256 + threadIdx.x;   // 256 blocks
    float4 v = reinterpret_cast<const float4*>(x)[i];
    ushort4v o = { bf_trunc(v.x), bf_trunc(v.y), bf_trunc(v.z), bf_trunc(v.w) };
    reinterpret_cast<ushort4v*>(xs)[i] = o;
}

// ---------------------------------------------------------------- k_fused
// Grid 256 = (o 0..127, h 0..1), 1024 thr = 16 waves, 1 block/CU.
// Phase 1 (GEMM): stage B-slice bf16 to LDS (4 passes, loads batched); wave w
//   computes m-rows w*16..w*16+15 via 16x16x32 MFMA; A-frags = short8 from xs
//   in two 16-deep bursts pinned by sched_barrier(0).
// Phase 2 (pair): identical to R9 k_pair, reading pm from LDS directly.
__global__ __launch_bounds__(1024, 4) void k_fused(const float* __restrict__ x,
                                                   const float* __restrict__ T,
                                                   const unsigned short* __restrict__ xs,
                                                   float* __restrict__ out) {
    const int blk = blockIdx.x;
    const int o   = blk & 127;
    const int h   = blk >> 7;
    const int tid = threadIdx.x;
    const int wave = tid >> 6, lane = tid & 63;
    const int l15 = lane & 15, q = lane >> 4;

    __shared__ unsigned short bs[16][XB];   // 33,024 B  (dead after GEMM)
    __shared__ __half2 pm[BATCH][8];        //  8,192 B  [b][kd/2]
    __shared__ float part[32][128];         // 16,384 B  [bsel][b1-local]

    // prologue: copy x row blk into out (cols 0..1023); blocks <-> rows 1:1
    if (tid < 256)
        reinterpret_cast<float4*>(out)[blk * 288 + tid] =
            reinterpret_cast<const float4*>(x)[blk * 256 + tid];

    // stage B: bs[n][k] = bf16(T[k][o*16+n]); 4 passes, loads batched first
    {
        const int kb = tid >> 2, n0 = (tid & 3) * 4;
        float4 tv[4];
        #pragma unroll
        for (int pass = 0; pass < 4; ++pass)
            tv[pass] = *reinterpret_cast<const float4*>(
                &T[(pass * 256 + kb) * TCOLS + o * KDIM + n0]);
        #pragma unroll
        for (int pass = 0; pass < 4; ++pass) {
            const int k = pass * 256 + kb;
            bs[n0 + 0][k] = bf_trunc(tv[pass].x);
            bs[n0 + 1][k] = bf_trunc(tv[pass].y);
            bs[n0 + 2][k] = bf_trunc(tv[pass].z);
            bs[n0 + 3][k] = bf_trunc(tv[pass].w);
        }
    }
    __syncthreads();

    // GEMM: A[m=l15][k=q*8+j] (m89/m91). Two 16-deep prefetch bursts.
    const unsigned short* xr = xs + (wave * 16 + l15) * INF + q * 8;

    f32x4 acc = {0.f, 0.f, 0.f, 0.f};
    {
        short8 a[16];
        // ---- half 0: ks 0..15 (imm offsets 0..1920B off one base)
        #pragma unroll
        for (int i = 0; i < 16; ++i)
            a[i] = *reinterpret_cast<const short8*>(xr + i * 32);
        __builtin_amdgcn_sched_barrier(0);   // loads stay hoisted above uses
        #pragma unroll
        for (int ks = 0; ks < 16; ++ks) {
            short8 bfr = *reinterpret_cast<const short8*>(&bs[l15][ks * 32 + q * 8]);
            acc = __builtin_amdgcn_mfma_f32_16x16x32_bf16(a[ks], bfr, acc, 0, 0, 0);
        }
        // ---- half 1: ks 16..31
        #pragma unroll
        for (int i = 0; i < 16; ++i)
            a[i] = *reinterpret_cast<const short8*>(xr + (16 + i) * 32);
        __builtin_amdgcn_sched_barrier(0);
        #pragma unroll
        for (int ks = 0; ks < 16; ++ks) {
            short8 bfr = *reinterpret_cast<const short8*>(&bs[l15][(16 + ks) * 32 + q * 8]);
            acc = __builtin_amdgcn_mfma_f32_16x16x32_bf16(a[ks], bfr, acc, 0, 0, 0);
        }
    }

    // D layout (m89/m91): col(=kd)=l15, row(=b within 16-tile)=q*4+r
    {
        __half* pmh = reinterpret_cast<__half*>(pm);
        #pragma unroll
        for (int r = 0; r < 4; ++r)
            pmh[(wave * 16 + q * 4 + r) * 16 + l15] = __float2half(acc[r]);
    }
    __syncthreads();

    // pair phase: i1 = tid&31, bsel = tid>>5; 4 b1-rows {h*128 + r*32 + i1}
    // vs b2 in [bsel*8, bsel*8+8). co read wave-uniform -> LDS broadcast.
    const int i1 = tid & 31;
    const int bsel = tid >> 5;            // 0..31
    __half2 my[4][8];
    #pragma unroll
    for (int r = 0; r < 4; ++r) {
        union { uint4 u[2]; __half2 hh[8]; } c;
        c.u[0] = *reinterpret_cast<const uint4*>(&pm[h * 128 + r * 32 + i1][0]);
        c.u[1] = *reinterpret_cast<const uint4*>(&pm[h * 128 + r * 32 + i1][4]);
        #pragma unroll
        for (int j = 0; j < 8; ++j) my[r][j] = c.hh[j];
    }

    float tot[4] = {0.f, 0.f, 0.f, 0.f};
    const int b2_lo = bsel * 8;
    #pragma unroll
    for (int b2 = b2_lo; b2 < b2_lo + 8; ++b2) {
        union { uint4 u[2]; __half2 hh[8]; } co;      // wave-uniform -> broadcast
        co.u[0] = *reinterpret_cast<const uint4*>(&pm[b2][0]);
        co.u[1] = *reinterpret_cast<const uint4*>(&pm[b2][4]);
        #pragma unroll
        for (int r = 0; r < 4; ++r) {
            __half2 e0 = __habs2(__hsub2(my[r][0], co.hh[0]));
            __half2 e1 = __habs2(__hsub2(my[r][1], co.hh[1]));
            __half2 e2 = __habs2(__hsub2(my[r][2], co.hh[2]));
            __half2 e3 = __habs2(__hsub2(my[r][3], co.hh[3]));
            e0 = __hadd2(e0, __habs2(__hsub2(my[r][4], co.hh[4])));
            e1 = __hadd2(e1, __habs2(__hsub2(my[r][5], co.hh[5])));
            e2 = __hadd2(e2, __habs2(__hsub2(my[r][6], co.hh[6])));
            e3 = __hadd2(e3, __habs2(__hsub2(my[r][7], co.hh[7])));
            __half2 es = __hadd2(__hadd2(e0, e1), __hadd2(e2, e3));
            float n = __low2float(es) + __high2float(es);
            tot[r] += __expf(-n);   // b2==b1: same pm row -> diff bitwise 0 -> +1 exact
        }
    }
    #pragma unroll
    for (int r = 0; r < 4; ++r)
        part[bsel][r * 32 + i1] = tot[r];
    __syncthreads();

    // epilogue: sum 32 bsel partials; -1 removes self-pair. One writer per (b,o).
    if (tid < 128) {
        float s = -1.0f;
        #pragma unroll
        for (int j = 0; j < 32; ++j) s += part[j][tid];
        out[(h * 128 + tid) * OCOLS + INF + o] = s;
    }
}

// ---------------------------------------------------------------- launch
extern "C" void kernel_launch(void* const* d_in, const int* in_sizes, int n_in,
                              void* d_out, int out_size, void* d_ws, size_t ws_size,
                              hipStream_t stream) {
    const float* x = (const float*)d_in[0];   // [256][1024]
    const float* T = (const float*)d_in[1];   // [1024][2048]
    float* out = (float*)d_out;               // [256][1152]
    unsigned short* xs = (unsigned short*)d_ws;  // [256][1024] bf16 = 512 KB

    k_prep<<<256, 256, 0, stream>>>(x, xs);
    k_fused<<<256, 1024, 0, stream>>>(x, T, xs, out);
}

// Round 3
// 86.741 us; speedup vs baseline: 1.1396x; 1.0000x over previous
//
#include <hip/hip_runtime.h>
#include <hip/hip_fp16.h>

// MinibatchDiscrimination  B=256, IN_F=1024, OUT_F=128, KD=16 (fp32 in/out)
// out[b] = concat(x[b], o_b[b]); o_b[b][o] = sum_b2 exp(-L1(m[b,o,:], m[b2,o,:])) - 1
//
// R12: three stall fixes on the fused kernel (inferred k_fused ~28 us vs
// ~10 us analytic floor; fill 41 us + ~15 us gaps are fixed harness cost).
//  1. pm rows padded 32 B -> 48 B: my-read b128 dword-phase starts go from
//     {0,8,16,24} (16 banks, 8-deep, R10 SQ_LDS_BANK_CONFLICT=819K) to
//     (i1*12)%32 = uniform coverage -> conflict-free, same instr count.
//  2. GEMM A-path: rolling 4x8 chunk double-buffer (refill issued right
//     after consumption) -> L2 pipe stays fed (per-CU floor ~3.8 us for
//     512 KB xs), vs two drain-then-compute 16-bursts.
//  3. Tails: co 2-stage register double-buffer; epilogue 32-serial-read
//     chain -> 2-stage parallel reduction (1024 thr sum-4, 128 thr sum-8);
//     x->out copy folded into k_prep.
// Numerics (R1-R11, absmax=0.0): bf16-trunc inputs -> bitwise-identical
// MFMA; cross-pair norms ~580 -> expf underflows to exact 0; self-pair diff
// bitwise 0 (same pm row) -> +1 exact, -1 in epilogue.

#define BATCH 256
#define INF   1024
#define OUTF  128
#define KDIM  16
#define TCOLS 2048
#define OCOLS 1152
#define XB    1032   // bs row = 2064 B: 16B-aligned, uniform bank coverage on
                     // b128 frag reads (R9, m136)
#define PMW   12     // pm row = 12 half2 = 48 B (first 8 used): 48=3*16 keeps
                     // b128 alignment; (i1*12)%32 start-phases hit all banks

typedef __attribute__((ext_vector_type(8))) short short8;
typedef __attribute__((ext_vector_type(4))) float f32x4;
typedef __attribute__((ext_vector_type(4))) unsigned short ushort4v;

__device__ inline unsigned short bf_trunc(float f) {
    return (unsigned short)(__float_as_uint(f) >> 16);
}

// ---------------------------------------------------------------- k_prep
// x fp32 [256][1024] -> xs bf16 [256][1024] (trunc) + x-copy into out cols
// 0..1023. One float4 per thread.
__global__ __launch_bounds__(256) void k_prep(const float* __restrict__ x,
                                              unsigned short* __restrict__ xs,
                                              float* __restrict__ out) {
    const int b = blockIdx.x, t = threadIdx.x;
    const int i = b * 256 + t;
    float4 v = reinterpret_cast<const float4*>(x)[i];
    ushort4v o4 = { bf_trunc(v.x), bf_trunc(v.y), bf_trunc(v.z), bf_trunc(v.w) };
    reinterpret_cast<ushort4v*>(xs)[i] = o4;
    reinterpret_cast<float4*>(out)[b * 288 + t] = v;   // out row = 288 float4
}

// ---------------------------------------------------------------- k_fused
// Grid 256 = (o 0..127, h 0..1), 1024 thr = 16 waves, 1 block/CU.
// Phase 1 (GEMM): stage B-slice bf16 to LDS; wave w computes m-rows
//   w*16..w*16+15 via 16x16x32 MFMA; A-frags = short8 from xs, rolling 4x8
//   chunk double-buffer.
// Phase 2 (pair): b1 = h*128 + r*32 + i1 (r=0..3), b2 in [bsel*8, bsel*8+8).
__global__ __launch_bounds__(1024, 4) void k_fused(const float* __restrict__ T,
                                                   const unsigned short* __restrict__ xs,
                                                   float* __restrict__ out) {
    const int blk = blockIdx.x;
    const int o   = blk & 127;
    const int h   = blk >> 7;
    const int tid = threadIdx.x;
    const int wave = tid >> 6, lane = tid & 63;
    const int l15 = lane & 15, q = lane >> 4;

    __shared__ unsigned short bs[16][XB];   // 33,024 B (dead after GEMM)
    __shared__ __half2 pm[BATCH][PMW];      // 12,288 B [b][kd/2 padded]
    __shared__ float part[32][128];         // 16,384 B [bsel][b1-local]

    // stage B: bs[n][k] = bf16(T[k][o*16+n]); loads batched, then cvt+store
    {
        const int kb = tid >> 2, n0 = (tid & 3) * 4;
        float4 tv[4];
        #pragma unroll
        for (int pass = 0; pass < 4; ++pass)
            tv[pass] = *reinterpret_cast<const float4*>(
                &T[(pass * 256 + kb) * TCOLS + o * KDIM + n0]);
        #pragma unroll
        for (int pass = 0; pass < 4; ++pass) {
            const int k = pass * 256 + kb;
            bs[n0 + 0][k] = bf_trunc(tv[pass].x);
            bs[n0 + 1][k] = bf_trunc(tv[pass].y);
            bs[n0 + 2][k] = bf_trunc(tv[pass].z);
            bs[n0 + 3][k] = bf_trunc(tv[pass].w);
        }
    }
    __syncthreads();

    // GEMM: A[m=l15][k=q*8+j] (m89/m91). Rolling 4x8 chunks (A/B dbuf).
    const unsigned short* xr = xs + (wave * 16 + l15) * INF + q * 8;

    f32x4 acc = {0.f, 0.f, 0.f, 0.f};
    {
        short8 A[8], Bb[8];
        #pragma unroll
        for (int i = 0; i < 8; ++i) A[i]  = *reinterpret_cast<const short8*>(xr + i * 32);
        #pragma unroll
        for (int i = 0; i < 8; ++i) Bb[i] = *reinterpret_cast<const short8*>(xr + (8 + i) * 32);
        __builtin_amdgcn_sched_barrier(0);   // keep bursts hoisted above uses

        // g0: consume A (ks 0..7), refill A <- ks 16..23
        #pragma unroll
        for (int ks = 0; ks < 8; ++ks) {
            short8 bfr = *reinterpret_cast<const short8*>(&bs[l15][ks * 32 + q * 8]);
            acc = __builtin_amdgcn_mfma_f32_16x16x32_bf16(A[ks], bfr, acc, 0, 0, 0);
        }
        #pragma unroll
        for (int i = 0; i < 8; ++i) A[i] = *reinterpret_cast<const short8*>(xr + (16 + i) * 32);
        // g1: consume Bb (ks 8..15), refill Bb <- ks 24..31
        #pragma unroll
        for (int ks = 8; ks < 16; ++ks) {
            short8 bfr = *reinterpret_cast<const short8*>(&bs[l15][ks * 32 + q * 8]);
            acc = __builtin_amdgcn_mfma_f32_16x16x32_bf16(Bb[ks - 8], bfr, acc, 0, 0, 0);
        }
        #pragma unroll
        for (int i = 0; i < 8; ++i) Bb[i] = *reinterpret_cast<const short8*>(xr + (24 + i) * 32);
        // g2: consume A (ks 16..23)
        #pragma unroll
        for (int ks = 16; ks < 24; ++ks) {
            short8 bfr = *reinterpret_cast<const short8*>(&bs[l15][ks * 32 + q * 8]);
            acc = __builtin_amdgcn_mfma_f32_16x16x32_bf16(A[ks - 16], bfr, acc, 0, 0, 0);
        }
        // g3: consume Bb (ks 24..31)
        #pragma unroll
        for (int ks = 24; ks < 32; ++ks) {
            short8 bfr = *reinterpret_cast<const short8*>(&bs[l15][ks * 32 + q * 8]);
            acc = __builtin_amdgcn_mfma_f32_16x16x32_bf16(Bb[ks - 24], bfr, acc, 0, 0, 0);
        }
    }

    // D layout (m89/m91): col(=kd)=l15, row(=b within 16-tile)=q*4+r
    {
        __half* pmh = reinterpret_cast<__half*>(pm);
        #pragma unroll
        for (int r = 0; r < 4; ++r)
            pmh[(wave * 16 + q * 4 + r) * (2 * PMW) + l15] = __float2half(acc[r]);
    }
    __syncthreads();

    // pair phase
    const int i1 = tid & 31;
    const int bsel = tid >> 5;            // 0..31
    __half2 my[4][8];
    #pragma unroll
    for (int r = 0; r < 4; ++r) {
        union { uint4 u[2]; __half2 hh[8]; } c;
        c.u[0] = *reinterpret_cast<const uint4*>(&pm[h * 128 + r * 32 + i1][0]);
        c.u[1] = *reinterpret_cast<const uint4*>(&pm[h * 128 + r * 32 + i1][4]);
        #pragma unroll
        for (int j = 0; j < 8; ++j) my[r][j] = c.hh[j];
    }

    union U16 { uint4 u[2]; __half2 hh[8]; };
    float tot[4] = {0.f, 0.f, 0.f, 0.f};
    const int b2_lo = bsel * 8;

    U16 c0, c1;
    c0.u[0] = *reinterpret_cast<const uint4*>(&pm[b2_lo][0]);
    c0.u[1] = *reinterpret_cast<const uint4*>(&pm[b2_lo][4]);

    #pragma unroll
    for (int ib = 0; ib < 8; ib += 2) {
        // prefetch odd partner while computing even
        c1.u[0] = *reinterpret_cast<const uint4*>(&pm[b2_lo + ib + 1][0]);
        c1.u[1] = *reinterpret_cast<const uint4*>(&pm[b2_lo + ib + 1][4]);
        #pragma unroll
        for (int r = 0; r < 4; ++r) {
            __half2 e0 = __habs2(__hsub2(my[r][0], c0.hh[0]));
            __half2 e1 = __habs2(__hsub2(my[r][1], c0.hh[1]));
            __half2 e2 = __habs2(__hsub2(my[r][2], c0.hh[2]));
            __half2 e3 = __habs2(__hsub2(my[r][3], c0.hh[3]));
            e0 = __hadd2(e0, __habs2(__hsub2(my[r][4], c0.hh[4])));
            e1 = __hadd2(e1, __habs2(__hsub2(my[r][5], c0.hh[5])));
            e2 = __hadd2(e2, __habs2(__hsub2(my[r][6], c0.hh[6])));
            e3 = __hadd2(e3, __habs2(__hsub2(my[r][7], c0.hh[7])));
            __half2 es = __hadd2(__hadd2(e0, e1), __hadd2(e2, e3));
            float n = __low2float(es) + __high2float(es);
            tot[r] += __expf(-n);   // b2==b1: same pm row -> diff bitwise 0 -> +1 exact
        }
        // prefetch next even while computing odd
        if (ib + 2 < 8) {
            c0.u[0] = *reinterpret_cast<const uint4*>(&pm[b2_lo + ib + 2][0]);
            c0.u[1] = *reinterpret_cast<const uint4*>(&pm[b2_lo + ib + 2][4]);
        }
        #pragma unroll
        for (int r = 0; r < 4; ++r) {
            __half2 e0 = __habs2(__hsub2(my[r][0], c1.hh[0]));
            __half2 e1 = __habs2(__hsub2(my[r][1], c1.hh[1]));
            __half2 e2 = __habs2(__hsub2(my[r][2], c1.hh[2]));
            __half2 e3 = __habs2(__hsub2(my[r][3], c1.hh[3]));
            e0 = __hadd2(e0, __habs2(__hsub2(my[r][4], c1.hh[4])));
            e1 = __hadd2(e1, __habs2(__hsub2(my[r][5], c1.hh[5])));
            e2 = __hadd2(e2, __habs2(__hsub2(my[r][6], c1.hh[6])));
            e3 = __hadd2(e3, __habs2(__hsub2(my[r][7], c1.hh[7])));
            __half2 es = __hadd2(__hadd2(e0, e1), __hadd2(e2, e3));
            float n = __low2float(es) + __high2float(es);
            tot[r] += __expf(-n);
        }
    }
    #pragma unroll
    for (int r = 0; r < 4; ++r)
        part[bsel][r * 32 + i1] = tot[r];
    __syncthreads();

    // epilogue: 2-stage parallel reduction over the 32 bsel partials.
    // stage 1: all 1024 threads; group g (0..7) sums part[g*4 .. g*4+3][b1]
    {
        const int g = tid >> 7, b1 = tid & 127;
        float s = part[g * 4 + 0][b1] + part[g * 4 + 1][b1]
                + part[g * 4 + 2][b1] + part[g * 4 + 3][b1];
        __syncthreads();               // all reads done before overwrite
        part[g * 4][b1] = s;
    }
    __syncthreads();
    // stage 2: 128 threads sum the 8 group partials; -1 removes self-pair
    if (tid < 128) {
        float s = -1.0f;
        #pragma unroll
        for (int g = 0; g < 8; ++g) s += part[g * 4][tid];
        out[(h * 128 + tid) * OCOLS + INF + o] = s;
    }
}

// ---------------------------------------------------------------- launch
extern "C" void kernel_launch(void* const* d_in, const int* in_sizes, int n_in,
                              void* d_out, int out_size, void* d_ws, size_t ws_size,
                              hipStream_t stream) {
    const float* x = (const float*)d_in[0];   // [256][1024]
    const float* T = (const float*)d_in[1];   // [1024][2048]
    float* out = (float*)d_out;               // [256][1152]
    unsigned short* xs = (unsigned short*)d_ws;  // [256][1024] bf16 = 512 KB

    k_prep<<<256, 256, 0, stream>>>(x, xs, out);
    k_fused<<<256, 1024, 0, stream>>>(T, xs, out);
}

// Round 4
// 83.064 us; speedup vs baseline: 1.1900x; 1.0443x over previous
//
#include <hip/hip_runtime.h>
#include <hip/hip_fp16.h>

// MinibatchDiscrimination  B=256, IN_F=1024, OUT_F=128, KD=16 (fp32 in/out)
// out[b] = concat(x[b], o_b[b]); o_b[b][o] = sum_b2 exp(-L1(m[b,o,:], m[b2,o,:])) - 1
//
// R13: back to SPLIT architecture, with all fixes applied.
//  Evidence: R11 vs R12 totals identical to 1 ns despite 3 scheduling fixes ->
//  fused k_fused (~28 us) is floor-limited by its per-CU byte amplification:
//  every block re-reads all 512 KB of xs (128 MB aggregate L2/L3 traffic) to
//  rebuild pm, >= 3.9 us/CU of L2-share before pair even starts, serialized
//  behind T-staging in one 1-block/CU kernel. Splitting computes m ONCE:
//   - k_gemm per-CU input 384 KB (2 blocks x (128 KB xs + 64 KB T));
//   - k_pair per-block input 8 KB (its pm slice) + pure VALU.
//  R9's split was 31 us due to two fixed bugs: k_gemm VGPR=32 load
//  serialization (fixed by R11 burst prefetch, proven -36% on fused GEMM) and
//  k_pair bank-conflicted my-reads + serial epilogue (R12 fixes, previously
//  applied where they weren't critical). A-burst now issued BEFORE the bs
//  barrier so xs L2 latency hides under T-staging.
// Numerics (R1-R12, absmax=0.0): bf16-trunc inputs -> bitwise-identical MFMA;
// cross-pair norms ~580 -> expf underflows to exact 0; self-pair diff bitwise
// 0 (same pm row) -> +1 exact, -1 in epilogue.

#define BATCH 256
#define INF   1024
#define OUTF  128
#define KDIM  16
#define TCOLS 2048
#define OCOLS 1152
#define XB    1032   // bs row = 2064 B: 16B-aligned, bank shift 4/row,
                     // b128 frag reads <=2-way aliased = free (m136)
#define PMW   12     // pm row = 12 half2 = 48 B (first 8 used): b128-aligned,
                     // (i1*12)%32 start-phases cover all banks

typedef __attribute__((ext_vector_type(8))) short short8;
typedef __attribute__((ext_vector_type(4))) float f32x4;
typedef __attribute__((ext_vector_type(4))) unsigned short ushort4v;

__device__ inline unsigned short bf_trunc(float f) {
    return (unsigned short)(__float_as_uint(f) >> 16);
}

// ---------------------------------------------------------------- k_prep
// x fp32 [256][1024] -> xs bf16 [256][1024] (trunc) + x-copy into out cols
// 0..1023. One float4 per thread.
__global__ __launch_bounds__(256) void k_prep(const float* __restrict__ x,
                                              unsigned short* __restrict__ xs,
                                              float* __restrict__ out) {
    const int b = blockIdx.x, t = threadIdx.x;
    const int i = b * 256 + t;
    float4 v = reinterpret_cast<const float4*>(x)[i];
    ushort4v o4 = { bf_trunc(v.x), bf_trunc(v.y), bf_trunc(v.z), bf_trunc(v.w) };
    reinterpret_cast<ushort4v*>(xs)[i] = o4;
    reinterpret_cast<float4*>(out)[b * 288 + t] = v;   // out row = 288 float4
}

// ---------------------------------------------------------------- k_gemm
// Block = (o 0..127, mq 0..3), 256 thr = 4 waves, 512 blocks = 2 blk/CU
// (launch_bounds(256,2) -> VGPR cap 256, burst prefetch fits).
// Wave w computes m-rows (mq*4+w)*16 .. +16 via 16x16x32 MFMA.
// A-burst 0 issued BEFORE the bs barrier: xs loads don't depend on bs, so
// their L2 latency drains under the T-stage + barrier.
__global__ __launch_bounds__(256, 2) void k_gemm(const float* __restrict__ T,
                                                 const unsigned short* __restrict__ xs,
                                                 __half* __restrict__ mh) {
    const int blk = blockIdx.x;
    const int o   = blk & 127;
    const int mq  = blk >> 7;
    const int tid = threadIdx.x;
    const int wave = tid >> 6, lane = tid & 63;
    const int l15 = lane & 15, q = lane >> 4;

    __shared__ unsigned short bs[16][XB];   // 33,024 B
    __shared__ __half pmout[64][16];        //  2,048 B

    const int mt = mq * 4 + wave;
    const unsigned short* xr = xs + (mt * 16 + l15) * INF + q * 8;

    short8 a[16];
    // A-burst 0 (ks 0..15): issue before staging so latency overlaps it
    #pragma unroll
    for (int i = 0; i < 16; ++i)
        a[i] = *reinterpret_cast<const short8*>(xr + i * 32);
    __builtin_amdgcn_sched_barrier(0);

    // stage B: bs[n][k] = bf16(T[k][o*16+n]); 4 groups x 4 batched loads
    {
        const int kb = tid >> 2, n0 = (tid & 3) * 4;
        #pragma unroll
        for (int g = 0; g < 4; ++g) {
            float4 tv[4];
            #pragma unroll
            for (int p = 0; p < 4; ++p)
                tv[p] = *reinterpret_cast<const float4*>(
                    &T[((g * 4 + p) * 64 + kb) * TCOLS + o * KDIM + n0]);
            #pragma unroll
            for (int p = 0; p < 4; ++p) {
                const int k = (g * 4 + p) * 64 + kb;
                bs[n0 + 0][k] = bf_trunc(tv[p].x);
                bs[n0 + 1][k] = bf_trunc(tv[p].y);
                bs[n0 + 2][k] = bf_trunc(tv[p].z);
                bs[n0 + 3][k] = bf_trunc(tv[p].w);
            }
        }
    }
    __syncthreads();

    // K-loop: consume burst 0, issue burst 1, consume burst 1.
    f32x4 acc = {0.f, 0.f, 0.f, 0.f};
    #pragma unroll
    for (int ks = 0; ks < 16; ++ks) {
        short8 bfr = *reinterpret_cast<const short8*>(&bs[l15][ks * 32 + q * 8]);
        acc = __builtin_amdgcn_mfma_f32_16x16x32_bf16(a[ks], bfr, acc, 0, 0, 0);
    }
    #pragma unroll
    for (int i = 0; i < 16; ++i)
        a[i] = *reinterpret_cast<const short8*>(xr + (16 + i) * 32);
    __builtin_amdgcn_sched_barrier(0);
    #pragma unroll
    for (int ks = 0; ks < 16; ++ks) {
        short8 bfr = *reinterpret_cast<const short8*>(&bs[l15][(16 + ks) * 32 + q * 8]);
        acc = __builtin_amdgcn_mfma_f32_16x16x32_bf16(a[ks], bfr, acc, 0, 0, 0);
    }

    // D layout (m89/m91): col(=kd)=l15, row(=b within 16-tile)=q*4+r
    #pragma unroll
    for (int r = 0; r < 4; ++r)
        pmout[wave * 16 + q * 4 + r][l15] = __float2half(acc[r]);
    __syncthreads();

    // coalesced copy-out -> mh[o][mq*64 + row][*]  (pair-native layout)
    if (tid < 128) {
        const int row = tid >> 1, hh = tid & 1;
        uint4 v = *reinterpret_cast<const uint4*>(&pmout[row][hh * 8]);
        *reinterpret_cast<uint4*>(&mh[o * (BATCH * KDIM) + (mq * 64 + row) * KDIM + hh * 8]) = v;
    }
}

// ---------------------------------------------------------------- k_pair
// Block = (o, h), 1024 thr, 1 blk/CU. Reads its 8 KB pm slice from mh.
// Thread: i1 = tid&31, bsel = tid>>5; owns 4 b1-rows {h*128 + r*32 + i1}
// vs b2 in [bsel*8, bsel*8+8). co read wave-uniform -> LDS broadcast.
__global__ __launch_bounds__(1024, 4) void k_pair(const __half* __restrict__ mh,
                                                  float* __restrict__ out) {
    const int blk = blockIdx.x;
    const int o   = blk & 127;
    const int h   = blk >> 7;
    const int tid = threadIdx.x;

    __shared__ __half2 pm[BATCH][PMW];      // 12,288 B (rows padded to 48 B)
    __shared__ float part[32][128];         // 16,384 B [bsel][b1-local]

    // load m-slice: contiguous 8 KB, 512 x uint4, into padded pm rows
    if (tid < 512) {
        uint4 v = *reinterpret_cast<const uint4*>(
            &mh[o * (BATCH * KDIM) + (tid >> 1) * KDIM + (tid & 1) * 8]);
        *reinterpret_cast<uint4*>(&pm[tid >> 1][(tid & 1) * 4]) = v;
    }
    __syncthreads();

    const int i1 = tid & 31;
    const int bsel = tid >> 5;            // 0..31
    __half2 my[4][8];
    #pragma unroll
    for (int r = 0; r < 4; ++r) {
        union { uint4 u[2]; __half2 hh[8]; } c;
        c.u[0] = *reinterpret_cast<const uint4*>(&pm[h * 128 + r * 32 + i1][0]);
        c.u[1] = *reinterpret_cast<const uint4*>(&pm[h * 128 + r * 32 + i1][4]);
        #pragma unroll
        for (int j = 0; j < 8; ++j) my[r][j] = c.hh[j];
    }

    union U16 { uint4 u[2]; __half2 hh[8]; };
    float tot[4] = {0.f, 0.f, 0.f, 0.f};
    const int b2_lo = bsel * 8;

    U16 c0, c1;
    c0.u[0] = *reinterpret_cast<const uint4*>(&pm[b2_lo][0]);
    c0.u[1] = *reinterpret_cast<const uint4*>(&pm[b2_lo][4]);

    #pragma unroll
    for (int ib = 0; ib < 8; ib += 2) {
        c1.u[0] = *reinterpret_cast<const uint4*>(&pm[b2_lo + ib + 1][0]);
        c1.u[1] = *reinterpret_cast<const uint4*>(&pm[b2_lo + ib + 1][4]);
        #pragma unroll
        for (int r = 0; r < 4; ++r) {
            __half2 e0 = __habs2(__hsub2(my[r][0], c0.hh[0]));
            __half2 e1 = __habs2(__hsub2(my[r][1], c0.hh[1]));
            __half2 e2 = __habs2(__hsub2(my[r][2], c0.hh[2]));
            __half2 e3 = __habs2(__hsub2(my[r][3], c0.hh[3]));
            e0 = __hadd2(e0, __habs2(__hsub2(my[r][4], c0.hh[4])));
            e1 = __hadd2(e1, __habs2(__hsub2(my[r][5], c0.hh[5])));
            e2 = __hadd2(e2, __habs2(__hsub2(my[r][6], c0.hh[6])));
            e3 = __hadd2(e3, __habs2(__hsub2(my[r][7], c0.hh[7])));
            __half2 es = __hadd2(__hadd2(e0, e1), __hadd2(e2, e3));
            float n = __low2float(es) + __high2float(es);
            tot[r] += __expf(-n);   // b2==b1: same pm row -> diff bitwise 0 -> +1 exact
        }
        if (ib + 2 < 8) {
            c0.u[0] = *reinterpret_cast<const uint4*>(&pm[b2_lo + ib + 2][0]);
            c0.u[1] = *reinterpret_cast<const uint4*>(&pm[b2_lo + ib + 2][4]);
        }
        #pragma unroll
        for (int r = 0; r < 4; ++r) {
            __half2 e0 = __habs2(__hsub2(my[r][0], c1.hh[0]));
            __half2 e1 = __habs2(__hsub2(my[r][1], c1.hh[1]));
            __half2 e2 = __habs2(__hsub2(my[r][2], c1.hh[2]));
            __half2 e3 = __habs2(__hsub2(my[r][3], c1.hh[3]));
            e0 = __hadd2(e0, __habs2(__hsub2(my[r][4], c1.hh[4])));
            e1 = __hadd2(e1, __habs2(__hsub2(my[r][5], c1.hh[5])));
            e2 = __hadd2(e2, __habs2(__hsub2(my[r][6], c1.hh[6])));
            e3 = __hadd2(e3, __habs2(__hsub2(my[r][7], c1.hh[7])));
            __half2 es = __hadd2(__hadd2(e0, e1), __hadd2(e2, e3));
            float n = __low2float(es) + __high2float(es);
            tot[r] += __expf(-n);
        }
    }
    #pragma unroll
    for (int r = 0; r < 4; ++r)
        part[bsel][r * 32 + i1] = tot[r];
    __syncthreads();

    // epilogue: 2-stage parallel reduction over the 32 bsel partials.
    {
        const int g = tid >> 7, b1 = tid & 127;
        float s = part[g * 4 + 0][b1] + part[g * 4 + 1][b1]
                + part[g * 4 + 2][b1] + part[g * 4 + 3][b1];
        __syncthreads();               // all reads done before overwrite
        part[g * 4][b1] = s;
    }
    __syncthreads();
    if (tid < 128) {
        float s = -1.0f;
        #pragma unroll
        for (int g = 0; g < 8; ++g) s += part[g * 4][tid];
        out[(h * 128 + tid) * OCOLS + INF + o] = s;
    }
}

// ---------------------------------------------------------------- launch
extern "C" void kernel_launch(void* const* d_in, const int* in_sizes, int n_in,
                              void* d_out, int out_size, void* d_ws, size_t ws_size,
                              hipStream_t stream) {
    const float* x = (const float*)d_in[0];   // [256][1024]
    const float* T = (const float*)d_in[1];   // [1024][2048]
    float* out = (float*)d_out;               // [256][1152]
    unsigned short* xs = (unsigned short*)d_ws;                  // 512 KB bf16
    __half* mh = (__half*)((char*)d_ws + (1u << 20));            // 1 MB fp16 [128][256][16]

    k_prep<<<256, 256, 0, stream>>>(x, xs, out);
    k_gemm<<<512, 256, 0, stream>>>(T, xs, mh);
    k_pair<<<256, 1024, 0, stream>>>(mh, out);
}